// Round 6
// baseline (1622.211 us; speedup 1.0000x reference)
//
#include <hip/hip_runtime.h>

typedef short bf16x8 __attribute__((ext_vector_type(8)));
typedef unsigned short u16x8 __attribute__((ext_vector_type(8)));
typedef float f32x4 __attribute__((ext_vector_type(4)));

#define MFMA16(a, b, c) __builtin_amdgcn_mfma_f32_16x16x32_bf16((a), (b), (c), 0, 0, 0)

#define SCALEF 0.17677669529663687f  // 32^-0.5

__device__ __forceinline__ unsigned short f2bf(float f) {
  union { float f; unsigned u; } v; v.f = f;
  unsigned r = v.u + 0x7fffu + ((v.u >> 16) & 1u);  // RNE
  return (unsigned short)(r >> 16);
}

__device__ __forceinline__ void gl_lds16(const void* g, void* l) {
  __builtin_amdgcn_global_load_lds(
      (const __attribute__((address_space(1))) void*)g,
      (__attribute__((address_space(3))) void*)l, 16, 0, 0);
}

// ---------- prep kernels ----------
__global__ __launch_bounds__(256) void transpose_cvt_k(const float* __restrict__ W,
    unsigned short* __restrict__ Wt, int K, int N) {
  int i = blockIdx.x * 256 + threadIdx.x;
  if (i >= N * K) return;
  int n = i / K, k = i - n * K;
  Wt[i] = f2bf(W[(long)k * N + n]);
}

// combined bias, fragment-permuted: cb2[w][h][q][lc*4+nt] = rpb[h][q][nt*16+lc]
//                                                         + mask[w][q][nt*16+lc]
__global__ __launch_bounds__(256) void build_cb2_k(const float* __restrict__ bt,
    const float* __restrict__ mask, float* __restrict__ cb2) {
  int i = blockIdx.x * 256 + threadIdx.x;          // 64*16*64*64 = 4194304
  if (i >= 64 * 16 * 64 * 64) return;
  int nt = i & 3, lc = (i >> 2) & 15, q = (i >> 6) & 63, h = (i >> 12) & 15, w = i >> 16;
  int k = nt * 16 + lc;
  int dh = (q >> 3) - (k >> 3) + 7;
  int dw = (q & 7) - (k & 7) + 7;
  cb2[i] = bt[(dh * 15 + dw) * 16 + h] + mask[w * 4096 + q * 64 + k];
}

// fp32 -> bf16 bulk convert, 8 elems/thread (32B read, 16B write)
__global__ __launch_bounds__(256) void cvt_bf16_k(const float* __restrict__ in,
    unsigned short* __restrict__ out, int n8) {
  int i = blockIdx.x * 256 + threadIdx.x;
  if (i >= n8) return;
  const float4* p = (const float4*)(in + (size_t)i * 8);
  float4 a = p[0], b = p[1];
  uint4 pk;
  pk.x = (unsigned)f2bf(a.x) | ((unsigned)f2bf(a.y) << 16);
  pk.y = (unsigned)f2bf(a.z) | ((unsigned)f2bf(a.w) << 16);
  pk.z = (unsigned)f2bf(b.x) | ((unsigned)f2bf(b.y) << 16);
  pk.w = (unsigned)f2bf(b.z) | ((unsigned)f2bf(b.w) << 16);
  *(uint4*)(out + (size_t)i * 8) = pk;
}

// ---------- GEMM body: C[M,N] = A[M,K] @ Bt[N,K]^T + bias (all-bf16 m97) ----
template <typename OT>
__device__ __forceinline__ void gemm_body(const unsigned short* __restrict__ A,
    const unsigned short* __restrict__ Bt, const float* __restrict__ bias,
    OT* __restrict__ C, int M, int N, int K)
{
  constexpr bool O_F32 = (sizeof(OT) == 4);

  __shared__ __align__(16) char smem[32768];
  unsigned short* Asm = (unsigned short*)smem;   // [128][64] swizzled, 16 KB
  unsigned short* Bsm = Asm + 8192;              // [128][64] swizzled, 16 KB

  const int tn = N >> 7;
  const int nbm = M >> 7;                        // 2048, divisible by 8
  const int g = blockIdx.x;
  const int xcd = g & 7;                         // hw XCD = blockIdx % 8
  const int s = g >> 3;
  const int bm = xcd * (nbm >> 3) + (s / tn);    // A-panel sharers on one XCD
  const int bn = s - (s / tn) * tn;

  const int tid = threadIdx.x;
  const int wave = tid >> 6, lane = tid & 63;
  const int wr = wave >> 1, wc = wave & 1;
  const int lg = lane >> 4, lc = lane & 15;

  const long rowBase = (long)bm * 128;
  const int colBase = bn * 128;
  const int KT = K >> 6;

  f32x4 acc[4][4];
#pragma unroll
  for (int i = 0; i < 4; ++i)
#pragma unroll
    for (int j = 0; j < 4; ++j)
      acc[i][j] = f32x4{0.f, 0.f, 0.f, 0.f};

  const int blr = lane >> 3;                     // row-in-8
  const int bsw = (lane & 7) ^ blr;              // pre-swizzled source chunk

  auto issueA = [&](int kt) {
#pragma unroll
    for (int j = 0; j < 4; ++j) {
      int r = j * 32 + wave * 8 + blr;
      gl_lds16(A + (rowBase + r) * (long)K + kt * 64 + bsw * 8,
               Asm + (j * 4 + wave) * 512);
    }
  };
  auto issueB = [&](int kt) {
#pragma unroll
    for (int j = 0; j < 4; ++j) {
      int r = j * 32 + wave * 8 + blr;
      gl_lds16(Bt + (long)(colBase + r) * K + kt * 64 + bsw * 8,
               Bsm + (j * 4 + wave) * 512);
    }
  };
  auto compute = [&]() {
#pragma unroll
    for (int ks = 0; ks < 2; ++ks) {
      const int ca = (ks * 4 + lg) ^ (lc & 7);   // swizzled read chunk
      bf16x8 af[4], bfr[4];
#pragma unroll
      for (int mt = 0; mt < 4; ++mt)
        af[mt] = *(const bf16x8*)(Asm + (wr * 64 + mt * 16 + lc) * 64 + ca * 8);
#pragma unroll
      for (int nt = 0; nt < 4; ++nt)
        bfr[nt] = *(const bf16x8*)(Bsm + (wc * 64 + nt * 16 + lc) * 64 + ca * 8);
#pragma unroll
      for (int mt = 0; mt < 4; ++mt)
#pragma unroll
        for (int nt = 0; nt < 4; ++nt)
          acc[mt][nt] = MFMA16(af[mt], bfr[nt], acc[mt][nt]);
    }
  };

  issueA(0); issueB(0);
  __syncthreads();

  for (int kt = 0; kt < KT; ++kt) {
    const bool more = (kt + 1 < KT);
    compute();
    __syncthreads();
    if (more) {
      issueA(kt + 1); issueB(kt + 1);
      __syncthreads();
    }
  }

  float bv[4];
#pragma unroll
  for (int nt = 0; nt < 4; ++nt)
    bv[nt] = bias[colBase + wc * 64 + nt * 16 + lc];

  if constexpr (O_F32) {
    float* Sf = (float*)smem;                    // [64][128] f32
#pragma unroll
    for (int h = 0; h < 2; ++h) {
      if (wr == h) {
#pragma unroll
        for (int mt = 0; mt < 4; ++mt)
#pragma unroll
          for (int nt = 0; nt < 4; ++nt)
#pragma unroll
            for (int r = 0; r < 4; ++r)
              Sf[(mt * 16 + lg * 4 + r) * 128 + wc * 64 + nt * 16 + lc] =
                  acc[mt][nt][r] + bv[nt];
      }
      __syncthreads();
#pragma unroll
      for (int p = 0; p < 8; ++p) {
        int ch = p * 256 + tid, row = ch >> 5, c = ch & 31;
        *(float4*)((float*)C + (rowBase + h * 64 + row) * N + colBase + c * 4) =
            *(const float4*)(Sf + row * 128 + c * 4);
      }
      __syncthreads();
    }
  } else {
    unsigned short* Su = (unsigned short*)smem;  // [64][128] bf16
#pragma unroll
    for (int h = 0; h < 2; ++h) {
      if (wr == h) {
#pragma unroll
        for (int mt = 0; mt < 4; ++mt)
#pragma unroll
          for (int nt = 0; nt < 4; ++nt)
#pragma unroll
            for (int r = 0; r < 4; ++r)
              Su[(mt * 16 + lg * 4 + r) * 128 + wc * 64 + nt * 16 + lc] =
                  f2bf(acc[mt][nt][r] + bv[nt]);
      }
      __syncthreads();
#pragma unroll
      for (int p = 0; p < 4; ++p) {
        int ch = p * 256 + tid, row = ch >> 4, c = ch & 15;
        *(uint4*)((unsigned short*)C + (rowBase + h * 64 + row) * N + colBase + c * 8) =
            *(const uint4*)(Su + row * 128 + c * 8);
      }
      __syncthreads();
    }
  }
}

__global__ __launch_bounds__(256, 4) void gemm_q_k(const unsigned short* __restrict__ A,
    const unsigned short* __restrict__ Bt, const float* __restrict__ bias,
    unsigned short* __restrict__ C, int M, int N, int K) {
  gemm_body<unsigned short>(A, Bt, bias, C, M, N, K);
}
__global__ __launch_bounds__(256, 4) void gemm_kv_k(const unsigned short* __restrict__ A,
    const unsigned short* __restrict__ Bt, const float* __restrict__ bias,
    unsigned short* __restrict__ C, int M, int N, int K) {
  gemm_body<unsigned short>(A, Bt, bias, C, M, N, K);
}
__global__ __launch_bounds__(256, 4) void gemm_out_k(const unsigned short* __restrict__ A,
    const unsigned short* __restrict__ Bt, const float* __restrict__ bias,
    float* __restrict__ C, int M, int N, int K) {
  gemm_body<float>(A, Bt, bias, C, M, N, K);
}

// ---------- fused window attention ----------
// grid = 4096 windows, 4 waves; wave w handles heads 4w..4w+3.
// Head-pipelined: Q/K frags double-buffered (issue h+1 under h's softmax/PV);
// V issued at iter start, consumed at post-softmax scatter. Combined bias cb2
// gives one coalesced float4 per softmax row. LDS 52224B -> 3 blocks/CU.
__global__ __launch_bounds__(256, 3) void attn_k(
    const unsigned short* __restrict__ qh,   // [B*64][512] bf16
    const unsigned short* __restrict__ kvh,  // [B*64][1024] bf16 (k | v)
    const float* __restrict__ cb2,           // [64][16][64][64] permuted f32
    unsigned short* __restrict__ x)          // [B*64][512] bf16
{
  constexpr int LP = 68;
  __shared__ unsigned short P[4][64][LP];
  __shared__ unsigned short Vt[4][32][LP];

  const int b = blockIdx.x;
  const int w = b & 63;
  const int tid = threadIdx.x;
  const int wave = tid >> 6, lane = tid & 63;
  const int lg = lane >> 4, lc = lane & 15;
  const long rowQ = (long)b * 64;

  bf16x8 qf[2][4], kf[2][4];
  u16x8 vr[4];

  auto loadQK = [&](int h, int s2) {
#pragma unroll
    for (int mt = 0; mt < 4; ++mt)
      qf[s2][mt] = *(const bf16x8*)(qh + (rowQ + mt * 16 + lc) * 512 + h * 32 + lg * 8);
#pragma unroll
    for (int nt = 0; nt < 4; ++nt)
      kf[s2][nt] = *(const bf16x8*)(kvh + (rowQ + nt * 16 + lc) * 1024 + h * 32 + lg * 8);
  };

  loadQK(wave * 4, 0);

#pragma unroll
  for (int hi = 0; hi < 4; ++hi) {
    const int cur = hi & 1;
    const int h = wave * 4 + hi;

    // issue V loads now; consumed at scatter after softmax (latency hidden)
    {
      const unsigned short* vp = kvh + (rowQ + lane) * 1024 + 512 + h * 32;
      vr[0] = *(const u16x8*)(vp);
      vr[1] = *(const u16x8*)(vp + 8);
      vr[2] = *(const u16x8*)(vp + 16);
      vr[3] = *(const u16x8*)(vp + 24);
    }

    // QK^T
    f32x4 acc[4][4];
#pragma unroll
    for (int mt = 0; mt < 4; ++mt)
#pragma unroll
      for (int nt = 0; nt < 4; ++nt)
        acc[mt][nt] = f32x4{0.f, 0.f, 0.f, 0.f};
#pragma unroll
    for (int mt = 0; mt < 4; ++mt)
#pragma unroll
      for (int nt = 0; nt < 4; ++nt)
        acc[mt][nt] = MFMA16(qf[cur][mt], kf[cur][nt], acc[mt][nt]);

    // prefetch next head's Q/K under softmax+PV
    if (hi < 3) loadQK(h + 1, cur ^ 1);

    // softmax: one coalesced float4 bias load per row
    const float* cbq = cb2 + (((size_t)(w * 16 + h)) << 12) + lc * 4;
    float pden[4][4];
#pragma unroll
    for (int mt = 0; mt < 4; ++mt) {
#pragma unroll
      for (int r = 0; r < 4; ++r) {
        const int qrow = mt * 16 + lg * 4 + r;
        f32x4 cb = *(const f32x4*)(cbq + qrow * 64);
        float sc[4];
#pragma unroll
        for (int nt = 0; nt < 4; ++nt)
          sc[nt] = acc[mt][nt][r] * SCALEF + cb[nt];
        float mx = fmaxf(fmaxf(sc[0], sc[1]), fmaxf(sc[2], sc[3]));
        mx = fmaxf(mx, __shfl_xor(mx, 1));
        mx = fmaxf(mx, __shfl_xor(mx, 2));
        mx = fmaxf(mx, __shfl_xor(mx, 4));
        mx = fmaxf(mx, __shfl_xor(mx, 8));
        float s = 0.f;
#pragma unroll
        for (int nt = 0; nt < 4; ++nt) { sc[nt] = __expf(sc[nt] - mx); s += sc[nt]; }
        s += __shfl_xor(s, 1);
        s += __shfl_xor(s, 2);
        s += __shfl_xor(s, 4);
        s += __shfl_xor(s, 8);
        pden[mt][r] = 1.f / s;
#pragma unroll
        for (int nt = 0; nt < 4; ++nt)
          P[wave][qrow][nt * 16 + lc] = f2bf(sc[nt]);
      }
    }

    // scatter V^T (vr completes under QK+softmax)
#pragma unroll
    for (int j = 0; j < 8; ++j) {
      Vt[wave][j][lane]      = vr[0][j];
      Vt[wave][8 + j][lane]  = vr[1][j];
      Vt[wave][16 + j][lane] = vr[2][j];
      Vt[wave][24 + j][lane] = vr[3][j];
    }

    // PV
    f32x4 xacc[4][2];
#pragma unroll
    for (int mt = 0; mt < 4; ++mt)
#pragma unroll
      for (int nt = 0; nt < 2; ++nt)
        xacc[mt][nt] = f32x4{0.f, 0.f, 0.f, 0.f};
#pragma unroll
    for (int ks = 0; ks < 2; ++ks) {
      bf16x8 pa[4], vb[2];
#pragma unroll
      for (int mt = 0; mt < 4; ++mt)
        pa[mt] = *(const bf16x8*)&P[wave][mt * 16 + lc][ks * 32 + lg * 8];
#pragma unroll
      for (int nt = 0; nt < 2; ++nt)
        vb[nt] = *(const bf16x8*)&Vt[wave][nt * 16 + lc][ks * 32 + lg * 8];
#pragma unroll
      for (int mt = 0; mt < 4; ++mt)
#pragma unroll
        for (int nt = 0; nt < 2; ++nt)
          xacc[mt][nt] = MFMA16(pa[mt], vb[nt], xacc[mt][nt]);
    }

    // normalize + store
#pragma unroll
    for (int mt = 0; mt < 4; ++mt)
#pragma unroll
      for (int nt = 0; nt < 2; ++nt)
#pragma unroll
        for (int r = 0; r < 4; ++r) {
          const int qrow = mt * 16 + lg * 4 + r;
          x[(rowQ + qrow) * 512 + h * 32 + nt * 16 + lc] =
              f2bf(xacc[mt][nt][r] * pden[mt][r]);
        }
  }
}

extern "C" void kernel_launch(void* const* d_in, const int* in_sizes, int n_in,
                              void* d_out, int out_size, void* d_ws, size_t ws_size,
                              hipStream_t stream) {
  const float* q    = (const float*)d_in[0];
  const float* kv   = (const float*)d_in[1];
  const float* mask = (const float*)d_in[2];
  const float* Wq   = (const float*)d_in[3];
  const float* bq   = (const float*)d_in[4];
  const float* Wkv  = (const float*)d_in[5];
  const float* bkv  = (const float*)d_in[6];
  const float* btab = (const float*)d_in[7];
  const float* Wp   = (const float*)d_in[8];
  const float* bp   = (const float*)d_in[9];
  float* out = (float*)d_out;

  const int M = 4096 * 64;  // 262144 rows

  char* ws = (char*)d_ws;
  // Layout: qh | kvh | scratch(kvbf -> qbf -> xb, time-shared) | weights | cb2
  const size_t OFF_QH   = 0;                               // 256 MB
  const size_t OFF_KVH  = OFF_QH + (size_t)M * 512 * 2;    // 512 MB
  const size_t OFF_SCR  = OFF_KVH + (size_t)M * 1024 * 2;  // 256 MB (time-shared)
  const size_t OFF_WQT  = OFF_SCR + (size_t)M * 512 * 2;
  const size_t OFF_WKVT = OFF_WQT + 512 * 512 * 2;
  const size_t OFF_WPT  = OFF_WKVT + 1024 * 512 * 2;
  const size_t OFF_CB2  = OFF_WPT + 512 * 512 * 2;         // 16.8 MB f32

  unsigned short* qh    = (unsigned short*)(ws + OFF_QH);
  unsigned short* kvh   = (unsigned short*)(ws + OFF_KVH);
  unsigned short* scr   = (unsigned short*)(ws + OFF_SCR); // kvbf / qbf / xb
  unsigned short* Wq_t  = (unsigned short*)(ws + OFF_WQT);
  unsigned short* Wkv_t = (unsigned short*)(ws + OFF_WKVT);
  unsigned short* Wp_t  = (unsigned short*)(ws + OFF_WPT);
  float* cb2f           = (float*)(ws + OFF_CB2);

  transpose_cvt_k<<<(512 * 512 + 255) / 256, 256, 0, stream>>>(Wq, Wq_t, 512, 512);
  transpose_cvt_k<<<(512 * 1024 + 255) / 256, 256, 0, stream>>>(Wkv, Wkv_t, 512, 1024);
  transpose_cvt_k<<<(512 * 512 + 255) / 256, 256, 0, stream>>>(Wp, Wp_t, 512, 512);
  build_cb2_k<<<(64 * 16 * 64 * 64) / 256, 256, 0, stream>>>(btab, mask, cb2f);

  const int n8 = M * 512 / 8;  // 16M chunks of 8 floats

  cvt_bf16_k<<<n8 / 256, 256, 0, stream>>>(kv, scr, n8);
  gemm_kv_k<<<(M / 128) * (1024 / 128), 256, 0, stream>>>(scr, Wkv_t, bkv, kvh, M, 1024, 512);

  cvt_bf16_k<<<n8 / 256, 256, 0, stream>>>(q, scr, n8);
  gemm_q_k<<<(M / 128) * (512 / 128), 256, 0, stream>>>(scr, Wq_t, bq, qh, M, 512, 512);

  attn_k<<<4096, 256, 0, stream>>>(qh, kvh, cb2f, scr);

  gemm_out_k<<<(M / 128) * (512 / 128), 256, 0, stream>>>(scr, Wp_t, bp, out, M, 512, 512);

  (void)in_sizes; (void)n_in; (void)out_size; (void)ws_size;
}